// Round 13
// baseline (4459.928 us; speedup 1.0000x reference)
//
#include <hip/hip_runtime.h>
#include <math.h>

#define NINP 64
#define NH 512
#define G4 2048   // 4*NH
#define T 64
#define BATCH 2048
#define LDIN 4097 // T*NINP+1
#define XCOLS 4096

typedef __bf16 bf16x8 __attribute__((ext_vector_type(8)));
typedef float f32x4 __attribute__((ext_vector_type(4)));
typedef unsigned short ushort8 __attribute__((ext_vector_type(8)));

__device__ __forceinline__ float sigmf(float x) { return 1.0f / (1.0f + expf(-x)); }

__device__ __forceinline__ unsigned int bfhi_bits(float f) {
    unsigned int u = __float_as_uint(f);
    return (u + 0x7fffu + ((u >> 16) & 1u)) >> 16;
}
__device__ __forceinline__ float bf_to_f(unsigned int bits) {
    return __uint_as_float(bits << 16);
}

// global -> LDS DMA, 16B per lane. LDS dest = wave-uniform base + lane*16.
__device__ __forceinline__ void gll16(const void* g, void* l) {
    __builtin_amdgcn_global_load_lds(
        (const __attribute__((address_space(1))) unsigned int*)g,
        (__attribute__((address_space(3))) unsigned int*)l, 16, 0, 0);
}

// ---------------------------------------------------------------------------
// R12 diagnosis: per-CU time == ds_read_b128 issue wall (~11 cyc/read, port
// saturated when 2 blocks/CU resident; solo = latency-bound 1.8x worse).
// Fixes combined here:
//  (1) 64x64 wave tiles (R11 geometry): 64 reads per 128x128x32 block-tile
//      (-33% vs R12's 96). 256 thr / 4 waves (2m x 2n), acc[4][4].
//  (2) ONE dispatch per superstep, 3 jobs [L2(s-4) | P1(s) | L1(s-2)],
//      L2 first (longest job starts earliest -> no straggler tail).
//      2 blocks/CU co-resident (LDS 2x67.5KB=135KB, launch_bounds(256,2)).
// h1 = mod-3 ring (L1 writes h1[s-1], L2 reads h1[s-3] concurrently).
// h2 projection runs in L2's prologue (h2(t) -> out[t-1]).
// XOR swizzle baked into global layout (conflicts~0). vmcnt(8) pipeline.
// Gate columns PERMUTED: n' = j*4+g. 2D XCD partition. t=0: K1=0 + zc.
// ---------------------------------------------------------------------------
#define OFF_ALO 4096
#define OFF_WHI 8192
#define OFF_WLO 12288
#define BUFSZ   16384   // ushorts per buffer (32768 B)

struct Job {
    const ushort *A0hi, *A0lo; int lda0;
    const ushort *W0hi, *W0lo; int K0;
    const ushort *A1hi, *A1lo; int lda1;
    const ushort *W1hi, *W1lo; int K1;
    const float *bias, *pv, *pc;
    float *c;
    ushort *hhi, *hlo;
    const ushort *ophi, *oplo;
    float *piadst, *odst;
    int ostride, zc;
};

__global__ __launch_bounds__(256, 2) void lstm_fused3_k(
    Job j0, Job j1, Job j2, int nA, int nAB,
    const float* __restrict__ Wl, const float* __restrict__ blv,
    const float* __restrict__ input)
{
    __shared__ __align__(16) ushort smem[33792];   // 67584 B (2x32KB bufs; Gs 128x132 f32)
    float* Gs = (float*)smem;

    const int tid = threadIdx.x;
    const int lane = tid & 63;
    const int wid = tid >> 6;        // 0..3

    Job j; int bid;
    if ((int)blockIdx.x < nA)       { j = j0; bid = blockIdx.x; }
    else if ((int)blockIdx.x < nAB) { j = j1; bid = blockIdx.x - nA; }
    else                            { j = j2; bid = blockIdx.x - nAB; }

    // 2D XCD-pinned tile mapping: xcd>>2 = m-half, xcd&3 = n-quarter
    const int xcd = bid & 7;
    const int loc = bid >> 3;                         // 0..31
    const int mblk = ((xcd >> 2) << 3) | (loc & 7);   // 0..15
    const int nblk = ((xcd & 3) << 2) | (loc >> 3);   // 0..15
    const int m0 = mblk * 128;
    const int n0 = nblk * 128;

    // ---- prologue: out-projection of previous h (2 rows per wave) ----
    if (j.ophi != nullptr) {
        const float4* wv = (const float4*)(Wl + lane * 8);
        float4 w0 = wv[0], w1 = wv[1];
        float wreg[8] = {w0.x, w0.y, w0.z, w0.w, w1.x, w1.y, w1.z, w1.w};
        #pragma unroll
        for (int r2 = 0; r2 < 2; ++r2) {
            int row = bid * 8 + wid * 2 + r2;
            int xr = (row >> 1) & 3;
            int colp = ((lane >> 2) * 32) + (((lane & 3) ^ xr) << 3);
            ushort8 hh8 = *(const ushort8*)&j.ophi[(size_t)row * NH + colp];
            ushort8 hl8 = *(const ushort8*)&j.oplo[(size_t)row * NH + colp];
            float s = 0.f;
            #pragma unroll
            for (int e = 0; e < 8; ++e) {
                float h = bf_to_f(hh8[e]) + bf_to_f(hl8[e]);
                s = fmaf(h, wreg[e], s);
            }
            #pragma unroll
            for (int off = 32; off > 0; off >>= 1) s += __shfl_down(s, off);
            if (lane == 0) {
                float proj = s + blv[0];
                if (j.odst) j.odst[(size_t)row * j.ostride] = proj;
                if (j.piadst) j.piadst[row] = fabsf(proj) * input[(size_t)row * LDIN + (LDIN - 1)];
            }
        }
    }

    // wave geometry: 2m x 2n, wave tile 64x64
    const int wm = wid >> 1;
    const int wn = wid & 1;
    const int fr = lane & 15;
    const int fg = lane >> 4;
    const int rdsw = (fr >> 1) & 3; // read swizzle (base rows multiple of 16)

    // staging geometry (256 threads, 2 passes of 64 rows each)
    const int srow = tid >> 2;      // 0..63
    const int aslot = tid & 3;

    const int nt0 = j.K0 >> 5;
    const int nt1 = j.K1 >> 5;
    const int NT = nt0 + nt1;

    auto stage = [&](int t, int buf) {
        const ushort *Ahi, *Alo, *Whi, *Wlo;
        int lda_, K_, kt;
        if (t < nt0) { Ahi = j.A0hi; Alo = j.A0lo; lda_ = j.lda0; K_ = j.K0; kt = t * 32;
                       Whi = j.W0hi; Wlo = j.W0lo; }
        else         { Ahi = j.A1hi; Alo = j.A1lo; lda_ = j.lda1; K_ = j.K1; kt = (t - nt0) * 32;
                       Whi = j.W1hi; Wlo = j.W1lo; }
        char* base = (char*)smem + buf * 32768;
        const size_t acol = (size_t)kt + aslot * 8;
        #pragma unroll
        for (int cc = 0; cc < 2; ++cc) {
            int grow = cc * 64 + srow;
            char* wb = base + cc * 4096 + wid * 1024;
            gll16(&Ahi[(size_t)(m0 + grow) * lda_ + acol], wb);
            gll16(&Alo[(size_t)(m0 + grow) * lda_ + acol], wb + 8192);
            gll16(&Whi[(size_t)(n0 + grow) * K_ + acol],   wb + 16384);
            gll16(&Wlo[(size_t)(n0 + grow) * K_ + acol],   wb + 24576);
        }
    };

    f32x4 acc[4][4] = {};
    int cur = 0;

    stage(0, 0);
    if (NT > 1) stage(1, 1);

    for (int t = 0; t < NT; ++t) {
        // counted wait: all but the newest 8 loads (stage t+1)
        if (t + 1 < NT) { asm volatile("s_waitcnt vmcnt(8)" ::: "memory"); }
        else            { asm volatile("s_waitcnt vmcnt(0)" ::: "memory"); }
        __builtin_amdgcn_s_barrier();

        const ushort* bp = smem + cur * BUFSZ;
        bf16x8 ah[4], al[4], wh[4], wl[4];
        #pragma unroll
        for (int im = 0; im < 4; ++im) {
            int off = (wm * 64 + im * 16 + fr) * 32 + ((fg ^ rdsw) << 3);
            ah[im] = *(const bf16x8*)&bp[off];
            al[im] = *(const bf16x8*)&bp[OFF_ALO + off];
        }
        #pragma unroll
        for (int in = 0; in < 4; ++in) {
            int off = (wn * 64 + in * 16 + fr) * 32 + ((fg ^ rdsw) << 3);
            wh[in] = *(const bf16x8*)&bp[OFF_WHI + off];
            wl[in] = *(const bf16x8*)&bp[OFF_WLO + off];
        }
        #pragma unroll
        for (int im = 0; im < 4; ++im)
            #pragma unroll
            for (int in = 0; in < 4; ++in)
                acc[im][in] = __builtin_amdgcn_mfma_f32_16x16x32_bf16(ah[im], wh[in], acc[im][in], 0, 0, 0);
        #pragma unroll
        for (int im = 0; im < 4; ++im)
            #pragma unroll
            for (int in = 0; in < 4; ++in)
                acc[im][in] = __builtin_amdgcn_mfma_f32_16x16x32_bf16(ah[im], wl[in], acc[im][in], 0, 0, 0);
        #pragma unroll
        for (int im = 0; im < 4; ++im)
            #pragma unroll
            for (int in = 0; in < 4; ++in)
                acc[im][in] = __builtin_amdgcn_mfma_f32_16x16x32_bf16(al[im], wh[in], acc[im][in], 0, 0, 0);

        asm volatile("" ::: "memory");
        __builtin_amdgcn_s_barrier();       // all waves done reading buf[cur]
        asm volatile("" ::: "memory");
        if (t + 2 < NT) stage(t + 2, cur);  // refill the buffer just consumed
        cur ^= 1;
    }

    // ---- epilogue stage 1: bias + pia, fragments -> LDS f32 [128][132] ----
    __syncthreads();   // full drain: smem reused as Gs
    #pragma unroll
    for (int im = 0; im < 4; ++im) {
        int rowl = wm * 64 + im * 16 + fg * 4;
        #pragma unroll
        for (int in = 0; in < 4; ++in) {
            int npl = wn * 64 + in * 16 + fr;
            int np = n0 + npl;
            float bias = j.bias[np];
            float pcv = (j.pc != nullptr) ? j.pc[np] : 0.0f;
            #pragma unroll
            for (int r = 0; r < 4; ++r) {
                float g = acc[im][in][r] + bias;
                if (j.pv != nullptr) g += j.pv[m0 + rowl + r] * pcv;
                Gs[(rowl + r) * 132 + npl] = g;
            }
        }
    }
    __syncthreads();

    // ---- epilogue stage 2: per-cell update (16 cells/thread); coalesced I/O ----
    {
        int brow = tid >> 1;            // 0..127
        int jh = (tid & 1) * 16;        // 16 j's per thread
        int jbase = (n0 >> 2) + jh;
        size_t rowb = (size_t)(m0 + brow) * NH;
        size_t idx = rowb + jbase;
        float co[16], cn[16], hn[16];
        if (j.zc) {
            #pragma unroll
            for (int e = 0; e < 16; ++e) co[e] = 0.0f;
        } else {
            #pragma unroll
            for (int k = 0; k < 4; ++k) {
                float4 cold = *(const float4*)&j.c[idx + k * 4];
                co[k * 4 + 0] = cold.x; co[k * 4 + 1] = cold.y;
                co[k * 4 + 2] = cold.z; co[k * 4 + 3] = cold.w;
            }
        }
        #pragma unroll
        for (int jj = 0; jj < 16; ++jj) {
            float4 gv = *(const float4*)&Gs[brow * 132 + (jh + jj) * 4];
            float cnv = sigmf(gv.y) * co[jj] + sigmf(gv.x) * tanhf(gv.z);
            cn[jj] = cnv;
            hn[jj] = sigmf(gv.w) * tanhf(cnv);
        }
        #pragma unroll
        for (int k = 0; k < 4; ++k) {
            float4 cs = {cn[k * 4], cn[k * 4 + 1], cn[k * 4 + 2], cn[k * 4 + 3]};
            *(float4*)&j.c[idx + k * 4] = cs;
        }
        int xb = (brow >> 1) & 3;
        int base32 = jbase & ~31;
        int g0 = (jbase >> 3) & 3;
        #pragma unroll
        for (int gi = 0; gi < 2; ++gi) {
            ushort8 hh, hl;
            #pragma unroll
            for (int e = 0; e < 8; ++e) {
                unsigned int hb = bfhi_bits(hn[gi * 8 + e]);
                hh[e] = (unsigned short)hb;
                hl[e] = (unsigned short)bfhi_bits(hn[gi * 8 + e] - bf_to_f(hb));
            }
            int colp = base32 | ((((g0 + gi) & 3) ^ xb) << 3);
            *(ushort8*)&j.hhi[rowb + colp] = hh;
            *(ushort8*)&j.hlo[rowb + colp] = hl;
        }
    }
}

// Standalone out-projection from XOR-permuted hi/lo split h, optional pia.
__global__ __launch_bounds__(256) void out_proj_hl(const ushort* __restrict__ hhi,
                                                   const ushort* __restrict__ hlo,
                                                   const float* __restrict__ Wl,
                                                   const float* __restrict__ blv,
                                                   const float* __restrict__ scaleBase,
                                                   float* __restrict__ piadst,
                                                   float* __restrict__ odst, int ostride)
{
    int wave = threadIdx.x >> 6;
    int lane = threadIdx.x & 63;
    int row = blockIdx.x * 4 + wave;
    int xr = (row >> 1) & 3;
    int colp = ((lane >> 2) * 32) + (((lane & 3) ^ xr) << 3);
    ushort8 hh8 = *(const ushort8*)&hhi[(size_t)row * NH + colp];
    ushort8 hl8 = *(const ushort8*)&hlo[(size_t)row * NH + colp];
    const float4* wv = (const float4*)(Wl + lane * 8);
    float4 w0 = wv[0], w1 = wv[1];
    float wreg[8] = {w0.x, w0.y, w0.z, w0.w, w1.x, w1.y, w1.z, w1.w};
    float s = 0.f;
    #pragma unroll
    for (int e = 0; e < 8; ++e) {
        float h = bf_to_f(hh8[e]) + bf_to_f(hl8[e]);
        s = fmaf(h, wreg[e], s);
    }
    #pragma unroll
    for (int off = 32; off > 0; off >>= 1) s += __shfl_down(s, off);
    if (lane == 0) {
        float proj = s + blv[0];
        if (odst) odst[(size_t)row * ostride] = proj;
        if (piadst) piadst[row] = fabsf(proj) * scaleBase[(size_t)row * LDIN + (LDIN - 1)];
    }
}

// Split W[4NH][ldw] into permuted bf16 hi/lo, n' = j*4+g, with XOR-permuted
// 8-elem groups within each 32-col K-block (group g stored at g ^ ((np>>1)&3)).
__global__ __launch_bounds__(256) void split_perm_w_k(const float* __restrict__ W,
                                                      ushort* __restrict__ whi,
                                                      ushort* __restrict__ wlo,
                                                      int ldw, int kshift)
{
    int idx = blockIdx.x * 256 + threadIdx.x;
    int K = 1 << kshift;
    int np = idx >> kshift;
    int k = idx & (K - 1);
    int ks = (k & ~31) | ((((k >> 3) & 3) ^ ((np >> 1) & 3)) << 3) | (k & 7);
    int orig = ((np & 3) << 9) | (np >> 2);
    float v = W[(size_t)orig * ldw + ks];
    unsigned int hb = bfhi_bits(v);
    whi[idx] = (unsigned short)hb;
    wlo[idx] = (unsigned short)bfhi_bits(v - bf_to_f(hb));
}

// Split input x into bf16 hi/lo [b][4096], XOR-permuted groups per 32-block.
__global__ __launch_bounds__(256) void split_x_k(const float* __restrict__ input,
                                                 ushort* __restrict__ xhi,
                                                 ushort* __restrict__ xlo)
{
    int idx = blockIdx.x * 256 + threadIdx.x;   // over BATCH*XCOLS
    int b = idx >> 12;
    int col = idx & (XCOLS - 1);
    int cs = (col & ~31) | ((((col >> 3) & 3) ^ ((b >> 1) & 3)) << 3) | (col & 7);
    float v = input[(size_t)b * LDIN + cs];
    unsigned int hb = bfhi_bits(v);
    xhi[idx] = (unsigned short)hb;
    xlo[idx] = (unsigned short)bfhi_bits(v - bf_to_f(hb));
}

__global__ __launch_bounds__(256) void bias_prep_k(const float* __restrict__ bih,
                                                   const float* __restrict__ bhh,
                                                   float* __restrict__ bperm)
{
    int np = blockIdx.x * 256 + threadIdx.x;
    int orig = ((np & 3) << 9) | (np >> 2);
    bperm[np] = bih[orig] + bhh[orig];
}

__global__ __launch_bounds__(256) void pc_prep_k(const float* __restrict__ Wih1,
                                                 float* __restrict__ pc)
{
    int np = blockIdx.x * 256 + threadIdx.x;
    int orig = ((np & 3) << 9) | (np >> 2);
    pc[np] = Wih1[(size_t)orig * (NINP + 1) + NINP];
}

extern "C" void kernel_launch(void* const* d_in, const int* in_sizes, int n_in,
                              void* d_out, int out_size, void* d_ws, size_t ws_size,
                              hipStream_t stream)
{
    const float* input = (const float*)d_in[0];
    const float* Wih_p = (const float*)d_in[1];
    const float* Whh_p = (const float*)d_in[2];
    const float* bih_p = (const float*)d_in[3];
    const float* bhh_p = (const float*)d_in[4];
    const float* Wih1  = (const float*)d_in[5];
    const float* Whh1  = (const float*)d_in[6];
    const float* bih1  = (const float*)d_in[7];
    const float* bhh1  = (const float*)d_in[8];
    const float* Wih2  = (const float*)d_in[9];
    const float* Whh2  = (const float*)d_in[10];
    const float* bih2  = (const float*)d_in[11];
    const float* bhh2  = (const float*)d_in[12];
    const float* Wl    = (const float*)d_in[13];
    const float* bl    = (const float*)d_in[14];
    float* out = (float*)d_out;

    const size_t HC = (size_t)BATCH * NH;       // 1M elems
    char* p = (char*)d_ws;
    auto alloc = [&](size_t bytes) { char* r = p; p += (bytes + 255) & ~(size_t)255; return r; };

    float* c_p = (float*)alloc(HC * 4);
    float* c1  = (float*)alloc(HC * 4);
    float* c2  = (float*)alloc(HC * 4);
    ushort* hps_hi[2]; ushort* hps_lo[2];
    ushort* h1s_hi[3]; ushort* h1s_lo[3];
    ushort* h2s_hi[2]; ushort* h2s_lo[2];
    for (int i = 0; i < 2; ++i) { hps_hi[i] = (ushort*)alloc(HC * 2); hps_lo[i] = (ushort*)alloc(HC * 2); }
    for (int i = 0; i < 3; ++i) { h1s_hi[i] = (ushort*)alloc(HC * 2); h1s_lo[i] = (ushort*)alloc(HC * 2); }
    for (int i = 0; i < 2; ++i) { h2s_hi[i] = (ushort*)alloc(HC * 2); h2s_lo[i] = (ushort*)alloc(HC * 2); }
    float* pias   = (float*)alloc((size_t)T * BATCH * 4);
    ushort* WhhP_hi = (ushort*)alloc((size_t)G4 * NH * 2);
    ushort* WhhP_lo = (ushort*)alloc((size_t)G4 * NH * 2);
    ushort* WihP_hi = (ushort*)alloc((size_t)G4 * NINP * 2);
    ushort* WihP_lo = (ushort*)alloc((size_t)G4 * NINP * 2);
    ushort* Whh1_hi = (ushort*)alloc((size_t)G4 * NH * 2);
    ushort* Whh1_lo = (ushort*)alloc((size_t)G4 * NH * 2);
    ushort* Wih1x_hi = (ushort*)alloc((size_t)G4 * NINP * 2);
    ushort* Wih1x_lo = (ushort*)alloc((size_t)G4 * NINP * 2);
    ushort* Wih2_hi = (ushort*)alloc((size_t)G4 * NH * 2);
    ushort* Wih2_lo = (ushort*)alloc((size_t)G4 * NH * 2);
    ushort* Whh2_hi = (ushort*)alloc((size_t)G4 * NH * 2);
    ushort* Whh2_lo = (ushort*)alloc((size_t)G4 * NH * 2);
    ushort* xhi = (ushort*)alloc((size_t)BATCH * XCOLS * 2);
    ushort* xlo = (ushort*)alloc((size_t)BATCH * XCOLS * 2);
    float* biasP = (float*)alloc(G4 * 4);
    float* bias1 = (float*)alloc(G4 * 4);
    float* bias2 = (float*)alloc(G4 * 4);
    float* pc1   = (float*)alloc(G4 * 4);

    // prep (no memset: t=0 jobs skip h-segments via K=0 and zero c via zc)
    split_perm_w_k<<<(G4 * NH) / 256, 256, 0, stream>>>(Whh_p, WhhP_hi, WhhP_lo, NH, 9);
    split_perm_w_k<<<(G4 * NINP) / 256, 256, 0, stream>>>(Wih_p, WihP_hi, WihP_lo, NINP, 6);
    split_perm_w_k<<<(G4 * NH) / 256, 256, 0, stream>>>(Whh1, Whh1_hi, Whh1_lo, NH, 9);
    split_perm_w_k<<<(G4 * NINP) / 256, 256, 0, stream>>>(Wih1, Wih1x_hi, Wih1x_lo, NINP + 1, 6);
    split_perm_w_k<<<(G4 * NH) / 256, 256, 0, stream>>>(Wih2, Wih2_hi, Wih2_lo, NH, 9);
    split_perm_w_k<<<(G4 * NH) / 256, 256, 0, stream>>>(Whh2, Whh2_hi, Whh2_lo, NH, 9);
    split_x_k<<<(BATCH * XCOLS) / 256, 256, 0, stream>>>(input, xhi, xlo);
    bias_prep_k<<<G4 / 256, 256, 0, stream>>>(bih_p, bhh_p, biasP);
    bias_prep_k<<<G4 / 256, 256, 0, stream>>>(bih1, bhh1, bias1);
    bias_prep_k<<<G4 / 256, 256, 0, stream>>>(bih2, bhh2, bias2);
    pc_prep_k<<<G4 / 256, 256, 0, stream>>>(Wih1, pc1);

    auto jobP1 = [&](int s) {
        Job jo = {};
        jo.A0hi = xhi + (size_t)s * NINP; jo.A0lo = xlo + (size_t)s * NINP; jo.lda0 = XCOLS;
        jo.W0hi = WihP_hi; jo.W0lo = WihP_lo; jo.K0 = NINP;
        jo.A1hi = hps_hi[s & 1]; jo.A1lo = hps_lo[s & 1]; jo.lda1 = NH;
        jo.W1hi = WhhP_hi; jo.W1lo = WhhP_lo; jo.K1 = (s == 0) ? 0 : NH;
        jo.bias = biasP; jo.pv = nullptr; jo.pc = nullptr;
        jo.c = c_p; jo.hhi = hps_hi[(s + 1) & 1]; jo.hlo = hps_lo[(s + 1) & 1];
        jo.ophi = (s > 0) ? hps_hi[s & 1] : nullptr; jo.oplo = hps_lo[s & 1];
        jo.piadst = (s > 0) ? (pias + (size_t)(s - 1) * BATCH) : nullptr;
        jo.odst = nullptr; jo.ostride = 0; jo.zc = (s == 0);
        return jo;
    };
    auto jobL1 = [&](int t) {
        Job jo = {};
        jo.A0hi = xhi + (size_t)t * NINP; jo.A0lo = xlo + (size_t)t * NINP; jo.lda0 = XCOLS;
        jo.W0hi = Wih1x_hi; jo.W0lo = Wih1x_lo; jo.K0 = NINP;
        jo.A1hi = h1s_hi[t % 3]; jo.A1lo = h1s_lo[t % 3]; jo.lda1 = NH;
        jo.W1hi = Whh1_hi; jo.W1lo = Whh1_lo; jo.K1 = (t == 0) ? 0 : NH;
        jo.bias = bias1; jo.pv = pias + (size_t)t * BATCH; jo.pc = pc1;
        jo.c = c1; jo.hhi = h1s_hi[(t + 1) % 3]; jo.hlo = h1s_lo[(t + 1) % 3];
        jo.ophi = nullptr; jo.oplo = nullptr;
        jo.piadst = nullptr; jo.odst = nullptr; jo.ostride = 0;
        jo.zc = (t == 0);
        return jo;
    };
    auto jobL2 = [&](int t) {
        Job jo = {};
        jo.A0hi = h1s_hi[(t + 1) % 3]; jo.A0lo = h1s_lo[(t + 1) % 3]; jo.lda0 = NH;
        jo.W0hi = Wih2_hi; jo.W0lo = Wih2_lo; jo.K0 = NH;
        jo.A1hi = h2s_hi[t & 1]; jo.A1lo = h2s_lo[t & 1]; jo.lda1 = NH;
        jo.W1hi = Whh2_hi; jo.W1lo = Whh2_lo; jo.K1 = (t == 0) ? 0 : NH;
        jo.bias = bias2; jo.pv = nullptr; jo.pc = nullptr;
        jo.c = c2; jo.hhi = h2s_hi[(t + 1) & 1]; jo.hlo = h2s_lo[(t + 1) & 1];
        jo.ophi = (t > 0) ? h2s_hi[t & 1] : nullptr; jo.oplo = h2s_lo[t & 1];
        jo.piadst = nullptr;
        jo.odst = (t > 0) ? (out + (t - 1)) : nullptr; jo.ostride = T + 1;
        jo.zc = (t == 0);
        return jo;
    };

    // One dispatch per superstep s: jobs [L2(s-4) | P1(s) | L1(s-2)].
    for (int s = 0; s <= 67; ++s) {
        Job j0 = {}, j1 = {}, j2 = {};
        int nL2 = 0, nP1 = 0, nL1 = 0;
        if (s >= 4)            { j0 = jobL2(s - 4); nL2 = 256; }
        if (s <= 63)           { j1 = jobP1(s);     nP1 = 256; }
        if (s >= 2 && s <= 65) { j2 = jobL1(s - 2); nL1 = 256; }
        int nA = nL2, nAB = nL2 + nP1, total = nL2 + nP1 + nL1;
        lstm_fused3_k<<<total, 256, 0, stream>>>(j0, j1, j2, nA, nAB, Wl, bl, input);
        if (s == 63) {
            // T1: proj h_p(64) -> pias[63] (needed by L1(63) at s=65) and raw
            // last_pia column out[:,T].
            out_proj_hl<<<BATCH / 4, 256, 0, stream>>>(hps_hi[0], hps_lo[0], Wl, bl,
                                                       input, pias + (size_t)63 * BATCH,
                                                       out + T, T + 1);
        }
    }
    // T4: proj h2(64) -> out[:,63].
    out_proj_hl<<<BATCH / 4, 256, 0, stream>>>(h2s_hi[0], h2s_lo[0], Wl, bl, input,
                                               nullptr, out + 63, T + 1);
}

// Round 14
// 3466.393 us; speedup vs baseline: 1.2866x; 1.2866x over previous
//
#include <hip/hip_runtime.h>
#include <math.h>

#define NINP 64
#define NH 512
#define G4 2048   // 4*NH
#define T 64
#define BATCH 2048
#define LDIN 4097 // T*NINP+1
#define XCOLS 4096

typedef _Float16 half8 __attribute__((ext_vector_type(8)));
typedef float f32x4 __attribute__((ext_vector_type(4)));
typedef unsigned short ushort8 __attribute__((ext_vector_type(8)));

__device__ __forceinline__ float sigmf(float x) { return 1.0f / (1.0f + expf(-x)); }

__device__ __forceinline__ unsigned short f2h_bits(float f) {
    _Float16 h = (_Float16)f;
    return __builtin_bit_cast(unsigned short, h);
}
__device__ __forceinline__ float h_to_f(unsigned short b) {
    return (float)__builtin_bit_cast(_Float16, b);
}

// global -> LDS DMA, 16B per lane. LDS dest = wave-uniform base + lane*16.
__device__ __forceinline__ void gll16(const void* g, void* l) {
    __builtin_amdgcn_global_load_lds(
        (const __attribute__((address_space(1))) unsigned int*)g,
        (__attribute__((address_space(3))) unsigned int*)l, 16, 0, 0);
}

// ---------------------------------------------------------------------------
// fp16 2-PRODUCT scheme (R13 diagnosis: 33% of MFMA peak; cut the work):
//   A (h/x) = fp16 hi + lo (error ~2^-22), W = single fp16 (fixed 2^-12
//   weight perturbation). C = Ahi*W + Alo*W : 2 MFMA passes (was 3),
//   3 staged planes (was 4), LDS reads 64KB/tile (was 96KB, 4m x 2n waves).
// Geometry: 512 thr / 8 waves (4m x 2n), block tile 128(b) x 128(n'),
// wave 32x64, acc[2][4], BK=32. LDS: 2 x 24KB buffers; Gs 128x132 f32.
// Schedule: R12's measured-best pairing: D1=[P1(s) | L2(s-2)] (512 blocks,
// 2/CU co-resident), D2=[L1(s-1)] (256 blocks).
// XOR swizzle baked into global layout (conflicts~0). vmcnt(3) pipeline.
// Gate columns PERMUTED: n' = j*4+g. 2D XCD partition. t=0: K1=0 + zc.
// ---------------------------------------------------------------------------
#define OFF_ALO 4096
#define OFF_W   8192
#define BUFSZ   12288   // ushorts per buffer (24576 B)

struct Job {
    const ushort *A0hi, *A0lo; int lda0;
    const ushort *W0; int K0;
    const ushort *A1hi, *A1lo; int lda1;
    const ushort *W1; int K1;
    const float *bias, *pv, *pc;
    float *c;
    ushort *hhi, *hlo;
    const ushort *ophi, *oplo;
    float *piadst, *odst;
    int ostride, zc;
};

__global__ __launch_bounds__(512, 4) void lstm_fused_k(
    Job ja, Job jb, int na,
    const float* __restrict__ Wl, const float* __restrict__ blv,
    const float* __restrict__ input)
{
    __shared__ __align__(16) ushort smem[33792];   // 67584 B (2x24KB bufs; Gs 128x132 f32)
    float* Gs = (float*)smem;

    const int tid = threadIdx.x;
    const int lane = tid & 63;
    const int wid = tid >> 6;        // 0..7
    const Job j = ((int)blockIdx.x < na) ? ja : jb;
    const int bid = ((int)blockIdx.x < na) ? blockIdx.x : (blockIdx.x - na);

    // 2D XCD-pinned tile mapping: xcd>>2 = m-half, xcd&3 = n-quarter
    const int xcd = bid & 7;
    const int loc = bid >> 3;                         // 0..31
    const int mblk = ((xcd >> 2) << 3) | (loc & 7);   // 0..15
    const int nblk = ((xcd & 3) << 2) | (loc >> 3);   // 0..15
    const int m0 = mblk * 128;
    const int n0 = nblk * 128;

    // ---- prologue: out-projection of previous h (1 row per wave) ----
    if (j.ophi != nullptr) {
        int row = bid * 8 + wid;
        int xr = (row >> 1) & 3;
        int colp = ((lane >> 2) * 32) + (((lane & 3) ^ xr) << 3);
        ushort8 hh8 = *(const ushort8*)&j.ophi[(size_t)row * NH + colp];
        ushort8 hl8 = *(const ushort8*)&j.oplo[(size_t)row * NH + colp];
        const float4* wv = (const float4*)(Wl + lane * 8);
        float4 w0 = wv[0], w1 = wv[1];
        float wreg[8] = {w0.x, w0.y, w0.z, w0.w, w1.x, w1.y, w1.z, w1.w};
        float s = 0.f;
        #pragma unroll
        for (int e = 0; e < 8; ++e) {
            float h = h_to_f(hh8[e]) + h_to_f(hl8[e]);
            s = fmaf(h, wreg[e], s);
        }
        #pragma unroll
        for (int off = 32; off > 0; off >>= 1) s += __shfl_down(s, off);
        if (lane == 0) {
            float proj = s + blv[0];
            if (j.odst) j.odst[(size_t)row * j.ostride] = proj;
            if (j.piadst) j.piadst[row] = fabsf(proj) * input[(size_t)row * LDIN + (LDIN - 1)];
        }
    }

    // wave geometry: 4m x 2n, wave tile 32x64
    const int wm = wid >> 1;        // 0..3
    const int wn = wid & 1;         // 0..1
    const int fr = lane & 15;
    const int fg = lane >> 4;
    const int rdsw = (fr >> 1) & 3; // read swizzle (row bases multiple of 16)

    // staging geometry: 512 threads, 1 gll16 per plane (Ahi, Alo, W)
    const int srow = tid >> 2;      // 0..127
    const int aslot = tid & 3;

    const int nt0 = j.K0 >> 5;
    const int nt1 = j.K1 >> 5;
    const int NT = nt0 + nt1;

    auto stage = [&](int t, int buf) {
        const ushort *Ahi, *Alo, *Wp;
        int lda_, K_, kt;
        if (t < nt0) { Ahi = j.A0hi; Alo = j.A0lo; lda_ = j.lda0; K_ = j.K0; kt = t * 32; Wp = j.W0; }
        else         { Ahi = j.A1hi; Alo = j.A1lo; lda_ = j.lda1; K_ = j.K1; kt = (t - nt0) * 32; Wp = j.W1; }
        char* wb = (char*)smem + buf * 24576 + wid * 1024;
        const size_t acol = (size_t)kt + aslot * 8;
        gll16(&Ahi[(size_t)(m0 + srow) * lda_ + acol], wb);
        gll16(&Alo[(size_t)(m0 + srow) * lda_ + acol], wb + 8192);
        gll16(&Wp[(size_t)(n0 + srow) * K_ + acol],    wb + 16384);
    };

    f32x4 acc[2][4] = {};
    int cur = 0;

    stage(0, 0);
    if (NT > 1) stage(1, 1);

    for (int t = 0; t < NT; ++t) {
        // counted wait: all but the newest 3 loads (stage t+1)
        if (t + 1 < NT) { asm volatile("s_waitcnt vmcnt(3)" ::: "memory"); }
        else            { asm volatile("s_waitcnt vmcnt(0)" ::: "memory"); }
        __builtin_amdgcn_s_barrier();

        const ushort* bp = smem + cur * BUFSZ;
        half8 ah[2], al[2], wv[4];
        #pragma unroll
        for (int im = 0; im < 2; ++im) {
            int off = (wm * 32 + im * 16 + fr) * 32 + ((fg ^ rdsw) << 3);
            ah[im] = *(const half8*)&bp[off];
            al[im] = *(const half8*)&bp[OFF_ALO + off];
        }
        #pragma unroll
        for (int in = 0; in < 4; ++in) {
            int off = (wn * 64 + in * 16 + fr) * 32 + ((fg ^ rdsw) << 3);
            wv[in] = *(const half8*)&bp[OFF_W + off];
        }
        #pragma unroll
        for (int im = 0; im < 2; ++im)
            #pragma unroll
            for (int in = 0; in < 4; ++in)
                acc[im][in] = __builtin_amdgcn_mfma_f32_16x16x32_f16(ah[im], wv[in], acc[im][in], 0, 0, 0);
        #pragma unroll
        for (int im = 0; im < 2; ++im)
            #pragma unroll
            for (int in = 0; in < 4; ++in)
                acc[im][in] = __builtin_amdgcn_mfma_f32_16x16x32_f16(al[im], wv[in], acc[im][in], 0, 0, 0);

        asm volatile("" ::: "memory");
        __builtin_amdgcn_s_barrier();       // all waves done reading buf[cur]
        asm volatile("" ::: "memory");
        if (t + 2 < NT) stage(t + 2, cur);  // refill the buffer just consumed
        cur ^= 1;
    }

    // ---- epilogue stage 1: bias + pia, fragments -> LDS f32 [128][132] ----
    __syncthreads();   // full drain: smem reused as Gs
    #pragma unroll
    for (int im = 0; im < 2; ++im) {
        int rowl = wm * 32 + im * 16 + fg * 4;
        #pragma unroll
        for (int in = 0; in < 4; ++in) {
            int npl = wn * 64 + in * 16 + fr;
            int np = n0 + npl;
            float bias = j.bias[np];
            float pcv = (j.pc != nullptr) ? j.pc[np] : 0.0f;
            #pragma unroll
            for (int r = 0; r < 4; ++r) {
                float g = acc[im][in][r] + bias;
                if (j.pv != nullptr) g += j.pv[m0 + rowl + r] * pcv;
                Gs[(rowl + r) * 132 + npl] = g;
            }
        }
    }
    __syncthreads();

    // ---- epilogue stage 2: per-cell update (8 cells/thread); coalesced I/O ----
    {
        int brow = tid >> 2;            // 0..127
        int jq = (tid & 3) * 8;         // 8 j's per thread (32 j per block)
        int jbase = (n0 >> 2) + jq;
        size_t rowb = (size_t)(m0 + brow) * NH;
        size_t idx = rowb + jbase;
        float co[8];
        if (j.zc) {
            #pragma unroll
            for (int e = 0; e < 8; ++e) co[e] = 0.0f;
        } else {
            float4 c0 = *(const float4*)&j.c[idx];
            float4 c1 = *(const float4*)&j.c[idx + 4];
            co[0] = c0.x; co[1] = c0.y; co[2] = c0.z; co[3] = c0.w;
            co[4] = c1.x; co[5] = c1.y; co[6] = c1.z; co[7] = c1.w;
        }
        float cn[8], hn[8];
        #pragma unroll
        for (int jj = 0; jj < 8; ++jj) {
            float4 gv = *(const float4*)&Gs[brow * 132 + (jq + jj) * 4];
            float cnv = sigmf(gv.y) * co[jj] + sigmf(gv.x) * tanhf(gv.z);
            cn[jj] = cnv;
            hn[jj] = sigmf(gv.w) * tanhf(cnv);
        }
        float4 cs0 = {cn[0], cn[1], cn[2], cn[3]};
        float4 cs1 = {cn[4], cn[5], cn[6], cn[7]};
        *(float4*)&j.c[idx] = cs0;
        *(float4*)&j.c[idx + 4] = cs1;
        ushort8 hh, hl;
        #pragma unroll
        for (int e = 0; e < 8; ++e) {
            unsigned short hb = f2h_bits(hn[e]);
            hh[e] = hb;
            hl[e] = f2h_bits(hn[e] - h_to_f(hb));
        }
        int xb = (brow >> 1) & 3;
        int colp = (jbase & ~31) | ((((jbase >> 3) & 3) ^ xb) << 3);
        *(ushort8*)&j.hhi[rowb + colp] = hh;
        *(ushort8*)&j.hlo[rowb + colp] = hl;
    }
}

// Standalone out-projection from XOR-permuted fp16 hi/lo h, optional pia.
__global__ __launch_bounds__(256) void out_proj_hl(const ushort* __restrict__ hhi,
                                                   const ushort* __restrict__ hlo,
                                                   const float* __restrict__ Wl,
                                                   const float* __restrict__ blv,
                                                   const float* __restrict__ scaleBase,
                                                   float* __restrict__ piadst,
                                                   float* __restrict__ odst, int ostride)
{
    int wave = threadIdx.x >> 6;
    int lane = threadIdx.x & 63;
    int row = blockIdx.x * 4 + wave;
    int xr = (row >> 1) & 3;
    int colp = ((lane >> 2) * 32) + (((lane & 3) ^ xr) << 3);
    ushort8 hh8 = *(const ushort8*)&hhi[(size_t)row * NH + colp];
    ushort8 hl8 = *(const ushort8*)&hlo[(size_t)row * NH + colp];
    const float4* wv = (const float4*)(Wl + lane * 8);
    float4 w0 = wv[0], w1 = wv[1];
    float wreg[8] = {w0.x, w0.y, w0.z, w0.w, w1.x, w1.y, w1.z, w1.w};
    float s = 0.f;
    #pragma unroll
    for (int e = 0; e < 8; ++e) {
        float h = h_to_f(hh8[e]) + h_to_f(hl8[e]);
        s = fmaf(h, wreg[e], s);
    }
    #pragma unroll
    for (int off = 32; off > 0; off >>= 1) s += __shfl_down(s, off);
    if (lane == 0) {
        float proj = s + blv[0];
        if (odst) odst[(size_t)row * ostride] = proj;
        if (piadst) piadst[row] = fabsf(proj) * scaleBase[(size_t)row * LDIN + (LDIN - 1)];
    }
}

// Split W[4NH][ldw] into permuted SINGLE fp16 plane, n' = j*4+g, with
// XOR-permuted 8-elem groups within each 32-col K-block.
__global__ __launch_bounds__(256) void split_perm_w_k(const float* __restrict__ W,
                                                      ushort* __restrict__ wout,
                                                      int ldw, int kshift)
{
    int idx = blockIdx.x * 256 + threadIdx.x;
    int K = 1 << kshift;
    int np = idx >> kshift;
    int k = idx & (K - 1);
    int ks = (k & ~31) | ((((k >> 3) & 3) ^ ((np >> 1) & 3)) << 3) | (k & 7);
    int orig = ((np & 3) << 9) | (np >> 2);
    wout[idx] = f2h_bits(W[(size_t)orig * ldw + ks]);
}

// Split input x into fp16 hi/lo [b][4096], XOR-permuted groups per 32-block.
__global__ __launch_bounds__(256) void split_x_k(const float* __restrict__ input,
                                                 ushort* __restrict__ xhi,
                                                 ushort* __restrict__ xlo)
{
    int idx = blockIdx.x * 256 + threadIdx.x;   // over BATCH*XCOLS
    int b = idx >> 12;
    int col = idx & (XCOLS - 1);
    int cs = (col & ~31) | ((((col >> 3) & 3) ^ ((b >> 1) & 3)) << 3) | (col & 7);
    float v = input[(size_t)b * LDIN + cs];
    unsigned short hb = f2h_bits(v);
    xhi[idx] = hb;
    xlo[idx] = f2h_bits(v - h_to_f(hb));
}

__global__ __launch_bounds__(256) void bias_prep_k(const float* __restrict__ bih,
                                                   const float* __restrict__ bhh,
                                                   float* __restrict__ bperm)
{
    int np = blockIdx.x * 256 + threadIdx.x;
    int orig = ((np & 3) << 9) | (np >> 2);
    bperm[np] = bih[orig] + bhh[orig];
}

__global__ __launch_bounds__(256) void pc_prep_k(const float* __restrict__ Wih1,
                                                 float* __restrict__ pc)
{
    int np = blockIdx.x * 256 + threadIdx.x;
    int orig = ((np & 3) << 9) | (np >> 2);
    pc[np] = Wih1[(size_t)orig * (NINP + 1) + NINP];
}

extern "C" void kernel_launch(void* const* d_in, const int* in_sizes, int n_in,
                              void* d_out, int out_size, void* d_ws, size_t ws_size,
                              hipStream_t stream)
{
    const float* input = (const float*)d_in[0];
    const float* Wih_p = (const float*)d_in[1];
    const float* Whh_p = (const float*)d_in[2];
    const float* bih_p = (const float*)d_in[3];
    const float* bhh_p = (const float*)d_in[4];
    const float* Wih1  = (const float*)d_in[5];
    const float* Whh1  = (const float*)d_in[6];
    const float* bih1  = (const float*)d_in[7];
    const float* bhh1  = (const float*)d_in[8];
    const float* Wih2  = (const float*)d_in[9];
    const float* Whh2  = (const float*)d_in[10];
    const float* bih2  = (const float*)d_in[11];
    const float* bhh2  = (const float*)d_in[12];
    const float* Wl    = (const float*)d_in[13];
    const float* bl    = (const float*)d_in[14];
    float* out = (float*)d_out;

    const size_t HC = (size_t)BATCH * NH;       // 1M elems
    char* p = (char*)d_ws;
    auto alloc = [&](size_t bytes) { char* r = p; p += (bytes + 255) & ~(size_t)255; return r; };

    float* c_p = (float*)alloc(HC * 4);
    float* c1  = (float*)alloc(HC * 4);
    float* c2  = (float*)alloc(HC * 4);
    ushort* hps_hi[2]; ushort* hps_lo[2];
    ushort* h1s_hi[2]; ushort* h1s_lo[2];
    ushort* h2s_hi[2]; ushort* h2s_lo[2];
    for (int i = 0; i < 2; ++i) { hps_hi[i] = (ushort*)alloc(HC * 2); hps_lo[i] = (ushort*)alloc(HC * 2); }
    for (int i = 0; i < 2; ++i) { h1s_hi[i] = (ushort*)alloc(HC * 2); h1s_lo[i] = (ushort*)alloc(HC * 2); }
    for (int i = 0; i < 2; ++i) { h2s_hi[i] = (ushort*)alloc(HC * 2); h2s_lo[i] = (ushort*)alloc(HC * 2); }
    float* pias   = (float*)alloc((size_t)T * BATCH * 4);
    ushort* WhhP_h = (ushort*)alloc((size_t)G4 * NH * 2);
    ushort* WihP_h = (ushort*)alloc((size_t)G4 * NINP * 2);
    ushort* Whh1_h = (ushort*)alloc((size_t)G4 * NH * 2);
    ushort* Wih1x_h = (ushort*)alloc((size_t)G4 * NINP * 2);
    ushort* Wih2_h = (ushort*)alloc((size_t)G4 * NH * 2);
    ushort* Whh2_h = (ushort*)alloc((size_t)G4 * NH * 2);
    ushort* xhi = (ushort*)alloc((size_t)BATCH * XCOLS * 2);
    ushort* xlo = (ushort*)alloc((size_t)BATCH * XCOLS * 2);
    float* biasP = (float*)alloc(G4 * 4);
    float* bias1 = (float*)alloc(G4 * 4);
    float* bias2 = (float*)alloc(G4 * 4);
    float* pc1   = (float*)alloc(G4 * 4);

    // prep (no memset: t=0 jobs skip h-segments via K=0 and zero c via zc)
    split_perm_w_k<<<(G4 * NH) / 256, 256, 0, stream>>>(Whh_p, WhhP_h, NH, 9);
    split_perm_w_k<<<(G4 * NINP) / 256, 256, 0, stream>>>(Wih_p, WihP_h, NINP, 6);
    split_perm_w_k<<<(G4 * NH) / 256, 256, 0, stream>>>(Whh1, Whh1_h, NH, 9);
    split_perm_w_k<<<(G4 * NINP) / 256, 256, 0, stream>>>(Wih1, Wih1x_h, NINP + 1, 6);
    split_perm_w_k<<<(G4 * NH) / 256, 256, 0, stream>>>(Wih2, Wih2_h, NH, 9);
    split_perm_w_k<<<(G4 * NH) / 256, 256, 0, stream>>>(Whh2, Whh2_h, NH, 9);
    split_x_k<<<(BATCH * XCOLS) / 256, 256, 0, stream>>>(input, xhi, xlo);
    bias_prep_k<<<G4 / 256, 256, 0, stream>>>(bih_p, bhh_p, biasP);
    bias_prep_k<<<G4 / 256, 256, 0, stream>>>(bih1, bhh1, bias1);
    bias_prep_k<<<G4 / 256, 256, 0, stream>>>(bih2, bhh2, bias2);
    pc_prep_k<<<G4 / 256, 256, 0, stream>>>(Wih1, pc1);

    auto jobP1 = [&](int s) {
        Job jo = {};
        jo.A0hi = xhi + (size_t)s * NINP; jo.A0lo = xlo + (size_t)s * NINP; jo.lda0 = XCOLS;
        jo.W0 = WihP_h; jo.K0 = NINP;
        jo.A1hi = hps_hi[s & 1]; jo.A1lo = hps_lo[s & 1]; jo.lda1 = NH;
        jo.W1 = WhhP_h; jo.K1 = (s == 0) ? 0 : NH;
        jo.bias = biasP; jo.pv = nullptr; jo.pc = nullptr;
        jo.c = c_p; jo.hhi = hps_hi[(s + 1) & 1]; jo.hlo = hps_lo[(s + 1) & 1];
        jo.ophi = (s > 0) ? hps_hi[s & 1] : nullptr; jo.oplo = hps_lo[s & 1];
        jo.piadst = (s > 0) ? (pias + (size_t)(s - 1) * BATCH) : nullptr;
        jo.odst = nullptr; jo.ostride = 0; jo.zc = (s == 0);
        return jo;
    };
    auto jobL1 = [&](int t) {
        Job jo = {};
        jo.A0hi = xhi + (size_t)t * NINP; jo.A0lo = xlo + (size_t)t * NINP; jo.lda0 = XCOLS;
        jo.W0 = Wih1x_h; jo.K0 = NINP;
        jo.A1hi = h1s_hi[t & 1]; jo.A1lo = h1s_lo[t & 1]; jo.lda1 = NH;
        jo.W1 = Whh1_h; jo.K1 = (t == 0) ? 0 : NH;
        jo.bias = bias1; jo.pv = pias + (size_t)t * BATCH; jo.pc = pc1;
        jo.c = c1; jo.hhi = h1s_hi[(t + 1) & 1]; jo.hlo = h1s_lo[(t + 1) & 1];
        jo.ophi = (t >= 1) ? h2s_hi[t & 1] : nullptr; jo.oplo = h2s_lo[t & 1];
        jo.piadst = nullptr;
        jo.odst = (t >= 1) ? (out + (t - 1)) : nullptr; jo.ostride = T + 1;
        jo.zc = (t == 0);
        return jo;
    };
    auto jobL2 = [&](int t) {
        Job jo = {};
        jo.A0hi = h1s_hi[(t + 1) & 1]; jo.A0lo = h1s_lo[(t + 1) & 1]; jo.lda0 = NH;
        jo.W0 = Wih2_h; jo.K0 = NH;
        jo.A1hi = h2s_hi[t & 1]; jo.A1lo = h2s_lo[t & 1]; jo.lda1 = NH;
        jo.W1 = Whh2_h; jo.K1 = (t == 0) ? 0 : NH;
        jo.bias = bias2; jo.pv = nullptr; jo.pc = nullptr;
        jo.c = c2; jo.hhi = h2s_hi[(t + 1) & 1]; jo.hlo = h2s_lo[(t + 1) & 1];
        jo.ophi = nullptr; jo.oplo = nullptr;
        jo.piadst = nullptr; jo.odst = nullptr; jo.ostride = 0;
        jo.zc = (t == 0);
        return jo;
    };

    // Main schedule (R12 pairing): D1 = [P1(s) || L2(s-2)]; D2 = [L1(s-1)].
    for (int s = 0; s < T; ++s) {
        Job a = jobP1(s);
        if (s >= 2) {
            Job b = jobL2(s - 2);
            lstm_fused_k<<<512, 512, 0, stream>>>(a, b, 256, Wl, bl, input);
        } else {
            lstm_fused_k<<<256, 512, 0, stream>>>(a, a, 256, Wl, bl, input);
        }
        if (s >= 1) {
            Job d = jobL1(s - 1);
            lstm_fused_k<<<256, 512, 0, stream>>>(d, d, 256, Wl, bl, input);
        }
    }
    // Tails.
    // T1: proj h_p(63) -> pias[63] and out[:,T] (raw last_pia column).
    out_proj_hl<<<BATCH / 4, 256, 0, stream>>>(hps_hi[0], hps_lo[0], Wl, bl, input,
                                               pias + (size_t)63 * BATCH, out + T, T + 1);
    // T2: [L1(63) || L2(62)]  (L1(63) prologue disabled)
    {
        Job a = jobL1(63);
        a.ophi = nullptr; a.oplo = nullptr; a.odst = nullptr;
        Job b = jobL2(62);
        lstm_fused_k<<<512, 512, 0, stream>>>(a, b, 256, Wl, bl, input);
    }
    // T3: L2(63), prologue projects h2(62) -> out[62].
    {
        Job a = jobL2(63);
        a.ophi = h2s_hi[1]; a.oplo = h2s_lo[1];
        a.odst = out + 62; a.ostride = T + 1;
        lstm_fused_k<<<256, 512, 0, stream>>>(a, a, 256, Wl, bl, input);
    }
    // T4: proj h2(63) -> out[:,63].
    out_proj_hl<<<BATCH / 4, 256, 0, stream>>>(h2s_hi[0], h2s_lo[0], Wl, bl, input,
                                               nullptr, out + 63, T + 1);
}

// Round 15
// 2987.947 us; speedup vs baseline: 1.4926x; 1.1601x over previous
//
#include <hip/hip_runtime.h>
#include <math.h>

#define NINP 64
#define NH 512
#define G4 2048   // 4*NH
#define T 64
#define BATCH 2048
#define LDIN 4097 // T*NINP+1
#define XCOLS 4096

typedef _Float16 half8 __attribute__((ext_vector_type(8)));
typedef float f32x4 __attribute__((ext_vector_type(4)));
typedef unsigned short ushort8 __attribute__((ext_vector_type(8)));
typedef unsigned short ushort4v __attribute__((ext_vector_type(4)));

__device__ __forceinline__ float sigmf(float x) { return 1.0f / (1.0f + expf(-x)); }

__device__ __forceinline__ unsigned short f2h_bits(float f) {
    _Float16 h = (_Float16)f;
    return __builtin_bit_cast(unsigned short, h);
}
__device__ __forceinline__ float h_to_f(unsigned short b) {
    return (float)__builtin_bit_cast(_Float16, b);
}

// global -> LDS DMA, 16B per lane. LDS dest = wave-uniform base + lane*16.
__device__ __forceinline__ void gll16(const void* g, void* l) {
    __builtin_amdgcn_global_load_lds(
        (const __attribute__((address_space(1))) unsigned int*)g,
        (__attribute__((address_space(3))) unsigned int*)l, 16, 0, 0);
}

// ---------------------------------------------------------------------------
// R14 diagnosis: LDS only ~63% busy at 2 blocks/CU; L1's solo dispatch is
// pure serial add-on. Fix: LDS 48KB (chunked epilogue) -> 3 blocks/CU ->
// ONE 768-block dispatch per superstep [L2(s-3) | L1(s-2) | P1(s)], all
// co-resident (R13's straggler failure was 67.5KB LDS capping at 2/CU).
// fp16 2-product scheme (R14): A = fp16 hi+lo, W = single fp16;
// C = Ahi*W + Alo*W. Geometry: 512 thr / 8 waves (4m x 2n), block tile
// 128x128, wave 32x64, acc[2][4], BK=32. LDS: 2 x 24KB stage bufs;
// epilogue Gs = [64][132] f32 (33.8KB) x 2 chunks, aliased.
// XOR swizzle baked into global layout (conflicts~0). vmcnt(3) pipeline.
// Gate columns PERMUTED: n' = j*4+g. 2D XCD partition. t=0: K1=0 + zc.
// h2-projection in L2's prologue; h_p-projection + pias in P1's prologue.
// ---------------------------------------------------------------------------
#define OFF_ALO 4096
#define OFF_W   8192
#define BUFSZ   12288   // ushorts per buffer (24576 B)

struct Job {
    const ushort *A0hi, *A0lo; int lda0;
    const ushort *W0; int K0;
    const ushort *A1hi, *A1lo; int lda1;
    const ushort *W1; int K1;
    const float *bias, *pv, *pc;
    float *c;
    ushort *hhi, *hlo;
    const ushort *ophi, *oplo;
    float *piadst, *odst;
    int ostride, zc;
};

__global__ __launch_bounds__(512, 6) void lstm_fused3_k(
    Job j0, Job j1, Job j2, int nA, int nAB,
    const float* __restrict__ Wl, const float* __restrict__ blv,
    const float* __restrict__ input)
{
    __shared__ __align__(16) ushort smem[2 * BUFSZ];   // 49152 B
    float* Gs = (float*)smem;                          // [64][132] chunk, aliased

    const int tid = threadIdx.x;
    const int lane = tid & 63;
    const int wid = tid >> 6;        // 0..7

    Job j; int bid;
    if ((int)blockIdx.x < nA)       { j = j0; bid = blockIdx.x; }
    else if ((int)blockIdx.x < nAB) { j = j1; bid = blockIdx.x - nA; }
    else                            { j = j2; bid = blockIdx.x - nAB; }

    // 2D XCD-pinned tile mapping: xcd>>2 = m-half, xcd&3 = n-quarter
    const int xcd = bid & 7;
    const int loc = bid >> 3;                         // 0..31
    const int mblk = ((xcd >> 2) << 3) | (loc & 7);   // 0..15
    const int nblk = ((xcd & 3) << 2) | (loc >> 3);   // 0..15
    const int m0 = mblk * 128;
    const int n0 = nblk * 128;

    // ---- prologue: out-projection of previous h (1 row per wave) ----
    if (j.ophi != nullptr) {
        int row = bid * 8 + wid;
        int xr = (row >> 1) & 3;
        int colp = ((lane >> 2) * 32) + (((lane & 3) ^ xr) << 3);
        ushort8 hh8 = *(const ushort8*)&j.ophi[(size_t)row * NH + colp];
        ushort8 hl8 = *(const ushort8*)&j.oplo[(size_t)row * NH + colp];
        const float4* wv = (const float4*)(Wl + lane * 8);
        float4 w0 = wv[0], w1 = wv[1];
        float wreg[8] = {w0.x, w0.y, w0.z, w0.w, w1.x, w1.y, w1.z, w1.w};
        float s = 0.f;
        #pragma unroll
        for (int e = 0; e < 8; ++e) {
            float h = h_to_f(hh8[e]) + h_to_f(hl8[e]);
            s = fmaf(h, wreg[e], s);
        }
        #pragma unroll
        for (int off = 32; off > 0; off >>= 1) s += __shfl_down(s, off);
        if (lane == 0) {
            float proj = s + blv[0];
            if (j.odst) j.odst[(size_t)row * j.ostride] = proj;
            if (j.piadst) j.piadst[row] = fabsf(proj) * input[(size_t)row * LDIN + (LDIN - 1)];
        }
    }

    // wave geometry: 4m x 2n, wave tile 32x64
    const int wm = wid >> 1;        // 0..3
    const int wn = wid & 1;         // 0..1
    const int fr = lane & 15;
    const int fg = lane >> 4;
    const int rdsw = (fr >> 1) & 3; // read swizzle (row bases multiple of 16)

    // staging geometry: 512 threads, 1 gll16 per plane (Ahi, Alo, W)
    const int srow = tid >> 2;      // 0..127
    const int aslot = tid & 3;

    const int nt0 = j.K0 >> 5;
    const int nt1 = j.K1 >> 5;
    const int NT = nt0 + nt1;

    auto stage = [&](int t, int buf) {
        const ushort *Ahi, *Alo, *Wp;
        int lda_, K_, kt;
        if (t < nt0) { Ahi = j.A0hi; Alo = j.A0lo; lda_ = j.lda0; K_ = j.K0; kt = t * 32; Wp = j.W0; }
        else         { Ahi = j.A1hi; Alo = j.A1lo; lda_ = j.lda1; K_ = j.K1; kt = (t - nt0) * 32; Wp = j.W1; }
        char* wb = (char*)smem + buf * 24576 + wid * 1024;
        const size_t acol = (size_t)kt + aslot * 8;
        gll16(&Ahi[(size_t)(m0 + srow) * lda_ + acol], wb);
        gll16(&Alo[(size_t)(m0 + srow) * lda_ + acol], wb + 8192);
        gll16(&Wp[(size_t)(n0 + srow) * K_ + acol],    wb + 16384);
    };

    f32x4 acc[2][4] = {};
    int cur = 0;

    stage(0, 0);
    if (NT > 1) stage(1, 1);

    for (int t = 0; t < NT; ++t) {
        // counted wait: all but the newest 3 loads (stage t+1)
        if (t + 1 < NT) { asm volatile("s_waitcnt vmcnt(3)" ::: "memory"); }
        else            { asm volatile("s_waitcnt vmcnt(0)" ::: "memory"); }
        __builtin_amdgcn_s_barrier();

        const ushort* bp = smem + cur * BUFSZ;
        half8 ah[2], al[2], wv[4];
        #pragma unroll
        for (int im = 0; im < 2; ++im) {
            int off = (wm * 32 + im * 16 + fr) * 32 + ((fg ^ rdsw) << 3);
            ah[im] = *(const half8*)&bp[off];
            al[im] = *(const half8*)&bp[OFF_ALO + off];
        }
        #pragma unroll
        for (int in = 0; in < 4; ++in) {
            int off = (wn * 64 + in * 16 + fr) * 32 + ((fg ^ rdsw) << 3);
            wv[in] = *(const half8*)&bp[OFF_W + off];
        }
        #pragma unroll
        for (int im = 0; im < 2; ++im)
            #pragma unroll
            for (int in = 0; in < 4; ++in)
                acc[im][in] = __builtin_amdgcn_mfma_f32_16x16x32_f16(ah[im], wv[in], acc[im][in], 0, 0, 0);
        #pragma unroll
        for (int im = 0; im < 2; ++im)
            #pragma unroll
            for (int in = 0; in < 4; ++in)
                acc[im][in] = __builtin_amdgcn_mfma_f32_16x16x32_f16(al[im], wv[in], acc[im][in], 0, 0, 0);

        asm volatile("" ::: "memory");
        __builtin_amdgcn_s_barrier();       // all waves done reading buf[cur]
        asm volatile("" ::: "memory");
        if (t + 2 < NT) stage(t + 2, cur);  // refill the buffer just consumed
        cur ^= 1;
    }

    // ---- epilogue: 2 chunks (im = 0,1), Gs = [64][132] f32 aliased ----
    #pragma unroll
    for (int ch = 0; ch < 2; ++ch) {
        __syncthreads();   // stage-buffer reads (or prev chunk) done
        // stage 1: bias + pia, fragments of chunk ch -> Gs
        {
            int g64 = wm * 16 + fg * 4;               // Gs row base
            int rowl = wm * 32 + ch * 16 + fg * 4;    // global row base
            #pragma unroll
            for (int in = 0; in < 4; ++in) {
                int npl = wn * 64 + in * 16 + fr;
                int np = n0 + npl;
                float bias = j.bias[np];
                float pcv = (j.pc != nullptr) ? j.pc[np] : 0.0f;
                #pragma unroll
                for (int r = 0; r < 4; ++r) {
                    float g = acc[ch][in][r] + bias;
                    if (j.pv != nullptr) g += j.pv[m0 + rowl + r] * pcv;
                    Gs[(g64 + r) * 132 + npl] = g;
                }
            }
        }
        __syncthreads();
        // stage 2: per-cell update (4 cells/thread), coalesced I/O
        {
            int r64 = tid >> 3;                  // 0..63 (Gs row)
            int jq = (tid & 7) * 4;              // j-quad within 32-j block
            int brow = (r64 >> 4) * 32 + ch * 16 + (r64 & 15);
            int jbase = (n0 >> 2) + jq;
            size_t rowb = (size_t)(m0 + brow) * NH;
            size_t idx = rowb + jbase;
            float co[4];
            if (j.zc) {
                co[0] = co[1] = co[2] = co[3] = 0.0f;
            } else {
                float4 c0 = *(const float4*)&j.c[idx];
                co[0] = c0.x; co[1] = c0.y; co[2] = c0.z; co[3] = c0.w;
            }
            float cn[4], hn[4];
            #pragma unroll
            for (int jj = 0; jj < 4; ++jj) {
                float4 gv = *(const float4*)&Gs[r64 * 132 + (jq + jj) * 4];
                float cnv = sigmf(gv.y) * co[jj] + sigmf(gv.x) * tanhf(gv.z);
                cn[jj] = cnv;
                hn[jj] = sigmf(gv.w) * tanhf(cnv);
            }
            float4 cs = {cn[0], cn[1], cn[2], cn[3]};
            *(float4*)&j.c[idx] = cs;
            ushort4v hh, hl;
            #pragma unroll
            for (int e = 0; e < 4; ++e) {
                unsigned short hb = f2h_bits(hn[e]);
                hh[e] = hb;
                hl[e] = f2h_bits(hn[e] - h_to_f(hb));
            }
            int xb = (brow >> 1) & 3;
            int colp = (jbase & ~31) | ((((jbase >> 3) & 3) ^ xb) << 3) | (jbase & 7);
            *(ushort4v*)&j.hhi[rowb + colp] = hh;
            *(ushort4v*)&j.hlo[rowb + colp] = hl;
        }
    }
}

// Standalone out-projection from XOR-permuted fp16 hi/lo h, optional pia.
__global__ __launch_bounds__(256) void out_proj_hl(const ushort* __restrict__ hhi,
                                                   const ushort* __restrict__ hlo,
                                                   const float* __restrict__ Wl,
                                                   const float* __restrict__ blv,
                                                   const float* __restrict__ scaleBase,
                                                   float* __restrict__ piadst,
                                                   float* __restrict__ odst, int ostride)
{
    int wave = threadIdx.x >> 6;
    int lane = threadIdx.x & 63;
    int row = blockIdx.x * 4 + wave;
    int xr = (row >> 1) & 3;
    int colp = ((lane >> 2) * 32) + (((lane & 3) ^ xr) << 3);
    ushort8 hh8 = *(const ushort8*)&hhi[(size_t)row * NH + colp];
    ushort8 hl8 = *(const ushort8*)&hlo[(size_t)row * NH + colp];
    const float4* wv = (const float4*)(Wl + lane * 8);
    float4 w0 = wv[0], w1 = wv[1];
    float wreg[8] = {w0.x, w0.y, w0.z, w0.w, w1.x, w1.y, w1.z, w1.w};
    float s = 0.f;
    #pragma unroll
    for (int e = 0; e < 8; ++e) {
        float h = h_to_f(hh8[e]) + h_to_f(hl8[e]);
        s = fmaf(h, wreg[e], s);
    }
    #pragma unroll
    for (int off = 32; off > 0; off >>= 1) s += __shfl_down(s, off);
    if (lane == 0) {
        float proj = s + blv[0];
        if (odst) odst[(size_t)row * ostride] = proj;
        if (piadst) piadst[row] = fabsf(proj) * scaleBase[(size_t)row * LDIN + (LDIN - 1)];
    }
}

// Split W[4NH][ldw] into permuted SINGLE fp16 plane, n' = j*4+g, with
// XOR-permuted 8-elem groups within each 32-col K-block.
__global__ __launch_bounds__(256) void split_perm_w_k(const float* __restrict__ W,
                                                      ushort* __restrict__ wout,
                                                      int ldw, int kshift)
{
    int idx = blockIdx.x * 256 + threadIdx.x;
    int K = 1 << kshift;
    int np = idx >> kshift;
    int k = idx & (K - 1);
    int ks = (k & ~31) | ((((k >> 3) & 3) ^ ((np >> 1) & 3)) << 3) | (k & 7);
    int orig = ((np & 3) << 9) | (np >> 2);
    wout[idx] = f2h_bits(W[(size_t)orig * ldw + ks]);
}

// Split input x into fp16 hi/lo [b][4096], XOR-permuted groups per 32-block.
__global__ __launch_bounds__(256) void split_x_k(const float* __restrict__ input,
                                                 ushort* __restrict__ xhi,
                                                 ushort* __restrict__ xlo)
{
    int idx = blockIdx.x * 256 + threadIdx.x;   // over BATCH*XCOLS
    int b = idx >> 12;
    int col = idx & (XCOLS - 1);
    int cs = (col & ~31) | ((((col >> 3) & 3) ^ ((b >> 1) & 3)) << 3) | (col & 7);
    float v = input[(size_t)b * LDIN + cs];
    unsigned short hb = f2h_bits(v);
    xhi[idx] = hb;
    xlo[idx] = f2h_bits(v - h_to_f(hb));
}

__global__ __launch_bounds__(256) void bias_prep_k(const float* __restrict__ bih,
                                                   const float* __restrict__ bhh,
                                                   float* __restrict__ bperm)
{
    int np = blockIdx.x * 256 + threadIdx.x;
    int orig = ((np & 3) << 9) | (np >> 2);
    bperm[np] = bih[orig] + bhh[orig];
}

__global__ __launch_bounds__(256) void pc_prep_k(const float* __restrict__ Wih1,
                                                 float* __restrict__ pc)
{
    int np = blockIdx.x * 256 + threadIdx.x;
    int orig = ((np & 3) << 9) | (np >> 2);
    pc[np] = Wih1[(size_t)orig * (NINP + 1) + NINP];
}

extern "C" void kernel_launch(void* const* d_in, const int* in_sizes, int n_in,
                              void* d_out, int out_size, void* d_ws, size_t ws_size,
                              hipStream_t stream)
{
    const float* input = (const float*)d_in[0];
    const float* Wih_p = (const float*)d_in[1];
    const float* Whh_p = (const float*)d_in[2];
    const float* bih_p = (const float*)d_in[3];
    const float* bhh_p = (const float*)d_in[4];
    const float* Wih1  = (const float*)d_in[5];
    const float* Whh1  = (const float*)d_in[6];
    const float* bih1  = (const float*)d_in[7];
    const float* bhh1  = (const float*)d_in[8];
    const float* Wih2  = (const float*)d_in[9];
    const float* Whh2  = (const float*)d_in[10];
    const float* bih2  = (const float*)d_in[11];
    const float* bhh2  = (const float*)d_in[12];
    const float* Wl    = (const float*)d_in[13];
    const float* bl    = (const float*)d_in[14];
    float* out = (float*)d_out;

    const size_t HC = (size_t)BATCH * NH;       // 1M elems
    char* p = (char*)d_ws;
    auto alloc = [&](size_t bytes) { char* r = p; p += (bytes + 255) & ~(size_t)255; return r; };

    float* c_p = (float*)alloc(HC * 4);
    float* c1  = (float*)alloc(HC * 4);
    float* c2  = (float*)alloc(HC * 4);
    ushort* hps_hi[2]; ushort* hps_lo[2];
    ushort* h1s_hi[2]; ushort* h1s_lo[2];
    ushort* h2s_hi[2]; ushort* h2s_lo[2];
    for (int i = 0; i < 2; ++i) { hps_hi[i] = (ushort*)alloc(HC * 2); hps_lo[i] = (ushort*)alloc(HC * 2); }
    for (int i = 0; i < 2; ++i) { h1s_hi[i] = (ushort*)alloc(HC * 2); h1s_lo[i] = (ushort*)alloc(HC * 2); }
    for (int i = 0; i < 2; ++i) { h2s_hi[i] = (ushort*)alloc(HC * 2); h2s_lo[i] = (ushort*)alloc(HC * 2); }
    float* pias   = (float*)alloc((size_t)T * BATCH * 4);
    ushort* WhhP_h = (ushort*)alloc((size_t)G4 * NH * 2);
    ushort* WihP_h = (ushort*)alloc((size_t)G4 * NINP * 2);
    ushort* Whh1_h = (ushort*)alloc((size_t)G4 * NH * 2);
    ushort* Wih1x_h = (ushort*)alloc((size_t)G4 * NINP * 2);
    ushort* Wih2_h = (ushort*)alloc((size_t)G4 * NH * 2);
    ushort* Whh2_h = (ushort*)alloc((size_t)G4 * NH * 2);
    ushort* xhi = (ushort*)alloc((size_t)BATCH * XCOLS * 2);
    ushort* xlo = (ushort*)alloc((size_t)BATCH * XCOLS * 2);
    float* biasP = (float*)alloc(G4 * 4);
    float* bias1 = (float*)alloc(G4 * 4);
    float* bias2 = (float*)alloc(G4 * 4);
    float* pc1   = (float*)alloc(G4 * 4);

    // prep (no memset: t=0 jobs skip h-segments via K=0 and zero c via zc)
    split_perm_w_k<<<(G4 * NH) / 256, 256, 0, stream>>>(Whh_p, WhhP_h, NH, 9);
    split_perm_w_k<<<(G4 * NINP) / 256, 256, 0, stream>>>(Wih_p, WihP_h, NINP, 6);
    split_perm_w_k<<<(G4 * NH) / 256, 256, 0, stream>>>(Whh1, Whh1_h, NH, 9);
    split_perm_w_k<<<(G4 * NINP) / 256, 256, 0, stream>>>(Wih1, Wih1x_h, NINP + 1, 6);
    split_perm_w_k<<<(G4 * NH) / 256, 256, 0, stream>>>(Wih2, Wih2_h, NH, 9);
    split_perm_w_k<<<(G4 * NH) / 256, 256, 0, stream>>>(Whh2, Whh2_h, NH, 9);
    split_x_k<<<(BATCH * XCOLS) / 256, 256, 0, stream>>>(input, xhi, xlo);
    bias_prep_k<<<G4 / 256, 256, 0, stream>>>(bih_p, bhh_p, biasP);
    bias_prep_k<<<G4 / 256, 256, 0, stream>>>(bih1, bhh1, bias1);
    bias_prep_k<<<G4 / 256, 256, 0, stream>>>(bih2, bhh2, bias2);
    pc_prep_k<<<G4 / 256, 256, 0, stream>>>(Wih1, pc1);

    auto jobP1 = [&](int s) {
        Job jo = {};
        jo.A0hi = xhi + (size_t)s * NINP; jo.A0lo = xlo + (size_t)s * NINP; jo.lda0 = XCOLS;
        jo.W0 = WihP_h; jo.K0 = NINP;
        jo.A1hi = hps_hi[s & 1]; jo.A1lo = hps_lo[s & 1]; jo.lda1 = NH;
        jo.W1 = WhhP_h; jo.K1 = (s == 0) ? 0 : NH;
        jo.bias = biasP; jo.pv = nullptr; jo.pc = nullptr;
        jo.c = c_p; jo.hhi = hps_hi[(s + 1) & 1]; jo.hlo = hps_lo[(s + 1) & 1];
        jo.ophi = (s > 0) ? hps_hi[s & 1] : nullptr; jo.oplo = hps_lo[s & 1];
        jo.piadst = (s > 0) ? (pias + (size_t)(s - 1) * BATCH) : nullptr;
        jo.odst = nullptr; jo.ostride = 0; jo.zc = (s == 0);
        return jo;
    };
    auto jobL1 = [&](int t) {
        Job jo = {};
        jo.A0hi = xhi + (size_t)t * NINP; jo.A0lo = xlo + (size_t)t * NINP; jo.lda0 = XCOLS;
        jo.W0 = Wih1x_h; jo.K0 = NINP;
        jo.A1hi = h1s_hi[t & 1]; jo.A1lo = h1s_lo[t & 1]; jo.lda1 = NH;
        jo.W1 = Whh1_h; jo.K1 = (t == 0) ? 0 : NH;
        jo.bias = bias1; jo.pv = pias + (size_t)t * BATCH; jo.pc = pc1;
        jo.c = c1; jo.hhi = h1s_hi[(t + 1) & 1]; jo.hlo = h1s_lo[(t + 1) & 1];
        jo.ophi = nullptr; jo.oplo = nullptr;
        jo.piadst = nullptr; jo.odst = nullptr; jo.ostride = 0;
        jo.zc = (t == 0);
        return jo;
    };
    auto jobL2 = [&](int t) {
        Job jo = {};
        jo.A0hi = h1s_hi[(t + 1) & 1]; jo.A0lo = h1s_lo[(t + 1) & 1]; jo.lda0 = NH;
        jo.W0 = Wih2_h; jo.K0 = NH;
        jo.A1hi = h2s_hi[t & 1]; jo.A1lo = h2s_lo[t & 1]; jo.lda1 = NH;
        jo.W1 = Whh2_h; jo.K1 = (t == 0) ? 0 : NH;
        jo.bias = bias2; jo.pv = nullptr; jo.pc = nullptr;
        jo.c = c2; jo.hhi = h2s_hi[(t + 1) & 1]; jo.hlo = h2s_lo[(t + 1) & 1];
        // prologue: project h2(t) -> out[t-1] (h2(t) lives in h2s[t&1], which
        // this job also reads as A1; written by L2(t-1) in a prior dispatch).
        jo.ophi = (t > 0) ? h2s_hi[t & 1] : nullptr; jo.oplo = h2s_lo[t & 1];
        jo.piadst = nullptr;
        jo.odst = (t > 0) ? (out + (t - 1)) : nullptr; jo.ostride = T + 1;
        jo.zc = (t == 0);
        return jo;
    };

    // One dispatch per superstep s: [L2(s-3) | L1(s-2) | P1(s)], all
    // co-resident at 3 blocks/CU. Dependencies cross dispatch boundaries only.
    for (int s = 0; s <= 66; ++s) {
        int nL2 = (s >= 3) ? 256 : 0;
        int nL1 = (s >= 2 && s <= 65) ? 256 : 0;
        int nP1 = (s <= 63) ? 256 : 0;
        Job j0 = {}, j1 = {}, j2 = {};
        if (nL2) j0 = jobL2(s - 3);
        if (nL1) j1 = jobL1(s - 2);
        if (nP1) j2 = jobP1(s);
        int nA = nL2, nAB = nL2 + nL1, total = nL2 + nL1 + nP1;
        lstm_fused3_k<<<total, 512, 0, stream>>>(j0, j1, j2, nA, nAB, Wl, bl, input);
        if (s == 63) {
            // T1: h_p(64) ready -> pias[63] (used by L1(63) at s=65) and raw
            // last_pia column out[:,T].
            out_proj_hl<<<BATCH / 4, 256, 0, stream>>>(hps_hi[0], hps_lo[0], Wl, bl,
                                                       input, pias + (size_t)63 * BATCH,
                                                       out + T, T + 1);
        }
    }
    // T4: proj h2(64) -> out[:,63].
    out_proj_hl<<<BATCH / 4, 256, 0, stream>>>(h2s_hi[0], h2s_lo[0], Wl, bl, input,
                                               nullptr, out + 63, T + 1);
}